// Round 1
// baseline (215.525 us; speedup 1.0000x reference)
//
#include <hip/hip_runtime.h>
#include <math.h>

#define DIM 128
#define NVOX (DIM*DIM*DIM)

__global__ __launch_bounds__(256) void warp_dti_kernel(
    const float* __restrict__ dti,
    const float* __restrict__ ddf,
    float* __restrict__ out)
{
    const int id = blockIdx.x * 256 + threadIdx.x;
    if (id >= NVOX) return;
    const int k = id & (DIM - 1);
    const int j = (id >> 7) & (DIM - 1);
    const int i = id >> 14;

    // ---------------- Jacobian: J = I + grad(ddf) (np.gradient semantics) ----
    const int im = (i > 0) ? i - 1 : 0, ip = (i < DIM - 1) ? i + 1 : DIM - 1;
    const int jm = (j > 0) ? j - 1 : 0, jp = (j < DIM - 1) ? j + 1 : DIM - 1;
    const int km = (k > 0) ? k - 1 : 0, kp = (k < DIM - 1) ? k + 1 : DIM - 1;
    const float si = (ip - im == 2) ? 0.5f : 1.0f;
    const float sj = (jp - jm == 2) ? 0.5f : 1.0f;
    const float sk = (kp - km == 2) ? 0.5f : 1.0f;

    const int l_ip = (ip << 14) | (j << 7) | k;
    const int l_im = (im << 14) | (j << 7) | k;
    const int l_jp = (i << 14) | (jp << 7) | k;
    const int l_jm = (i << 14) | (jm << 7) | k;
    const int l_kp = (i << 14) | (j << 7) | kp;
    const int l_km = (i << 14) | (j << 7) | km;

    float Jf[3][3];
    float u[3];
#pragma unroll
    for (int c = 0; c < 3; ++c) {
        const float* __restrict__ p = ddf + c * NVOX;
        u[c] = p[id];
        Jf[c][0] = (p[l_ip] - p[l_im]) * si;
        Jf[c][1] = (p[l_jp] - p[l_jm]) * sj;
        Jf[c][2] = (p[l_kp] - p[l_km]) * sk;
        Jf[c][c] += 1.0f;
    }

    // ---------------- Trilinear warp of dti (border padding) -----------------
    const float cx = fminf(fmaxf((float)i + u[0], 0.0f), (float)(DIM - 1));
    const float cy = fminf(fmaxf((float)j + u[1], 0.0f), (float)(DIM - 1));
    const float cz = fminf(fmaxf((float)k + u[2], 0.0f), (float)(DIM - 1));
    const float x0f = floorf(cx), y0f = floorf(cy), z0f = floorf(cz);
    const float fx = cx - x0f, fy = cy - y0f, fz = cz - z0f;
    const int x0 = (int)x0f, y0 = (int)y0f, z0 = (int)z0f;
    const int x1 = min(x0 + 1, DIM - 1);
    const int y1 = min(y0 + 1, DIM - 1);
    const int z1 = min(z0 + 1, DIM - 1);

    const int l000 = (x0 << 14) | (y0 << 7) | z0;
    const int l001 = (x0 << 14) | (y0 << 7) | z1;
    const int l010 = (x0 << 14) | (y1 << 7) | z0;
    const int l011 = (x0 << 14) | (y1 << 7) | z1;
    const int l100 = (x1 << 14) | (y0 << 7) | z0;
    const int l101 = (x1 << 14) | (y0 << 7) | z1;
    const int l110 = (x1 << 14) | (y1 << 7) | z0;
    const int l111 = (x1 << 14) | (y1 << 7) | z1;

    float w[6];
#pragma unroll
    for (int c = 0; c < 6; ++c) {
        const float* __restrict__ p = dti + c * NVOX;
        const float c00 = p[l000] * (1.0f - fz) + p[l001] * fz;
        const float c01 = p[l010] * (1.0f - fz) + p[l011] * fz;
        const float c10 = p[l100] * (1.0f - fz) + p[l101] * fz;
        const float c11 = p[l110] * (1.0f - fz) + p[l111] * fz;
        const float c0 = c00 * (1.0f - fy) + c01 * fy;
        const float c1 = c10 * (1.0f - fy) + c11 * fy;
        w[c] = c0 * (1.0f - fx) + c1 * fx;
    }

    // ---------------- Polar factor R = U @ Vh via scaled Newton (fp64) -------
    // X <- 0.5*(g*X + (1/(g*det))*cof(X)); X^{-T} = cof(X)/det.
    // Preserves singular vectors and sign(det) => converges to U@Vh of SVD.
    double X[9];
#pragma unroll
    for (int r = 0; r < 3; ++r)
#pragma unroll
        for (int c = 0; c < 3; ++c)
            X[r * 3 + c] = (double)Jf[r][c];

    for (int it = 0; it < 16; ++it) {
        double Cm[9];
        Cm[0] = X[4] * X[8] - X[5] * X[7];
        Cm[1] = X[5] * X[6] - X[3] * X[8];
        Cm[2] = X[3] * X[7] - X[4] * X[6];
        Cm[3] = X[2] * X[7] - X[1] * X[8];
        Cm[4] = X[0] * X[8] - X[2] * X[6];
        Cm[5] = X[1] * X[6] - X[0] * X[7];
        Cm[6] = X[1] * X[5] - X[2] * X[4];
        Cm[7] = X[2] * X[3] - X[0] * X[5];
        Cm[8] = X[0] * X[4] - X[1] * X[3];
        const double det = X[0] * Cm[0] + X[1] * Cm[1] + X[2] * Cm[2];
        if (!(fabs(det) > 1e-300)) break;  // exactly singular: measure zero

        double nX = 0.0, nC = 0.0;
#pragma unroll
        for (int t = 0; t < 9; ++t) { nX += X[t] * X[t]; nC += Cm[t] * Cm[t]; }
        // gamma = sqrt(||X^-1||_F / ||X||_F),  ||X^-1||_F = sqrt(nC)/|det|
        const double g = sqrt(sqrt(nC) / (fabs(det) * sqrt(nX)));
        const double a = 0.5 * g;
        const double b = 0.5 / (g * det);

        double diff2 = 0.0, n2 = 0.0;
#pragma unroll
        for (int t = 0; t < 9; ++t) {
            const double y = a * X[t] + b * Cm[t];
            const double d = y - X[t];
            diff2 += d * d;
            n2 += y * y;
            X[t] = y;
        }
        if (diff2 <= 1e-24 * n2) break;
    }

    // ---------------- Dp = R^T * M * R ---------------------------------------
    const double M00 = (double)w[0], M01 = (double)w[1], M11 = (double)w[2];
    const double M02 = (double)w[3], M12 = (double)w[4], M22 = (double)w[5];

    double P[9];  // P = M * R
    P[0] = M00 * X[0] + M01 * X[3] + M02 * X[6];
    P[1] = M00 * X[1] + M01 * X[4] + M02 * X[7];
    P[2] = M00 * X[2] + M01 * X[5] + M02 * X[8];
    P[3] = M01 * X[0] + M11 * X[3] + M12 * X[6];
    P[4] = M01 * X[1] + M11 * X[4] + M12 * X[7];
    P[5] = M01 * X[2] + M11 * X[5] + M12 * X[8];
    P[6] = M02 * X[0] + M12 * X[3] + M22 * X[6];
    P[7] = M02 * X[1] + M12 * X[4] + M22 * X[7];
    P[8] = M02 * X[2] + M12 * X[5] + M22 * X[8];

    // Dp[r][c] = sum_t R[t][r] * P[t][c]
    const double Dp00 = X[0] * P[0] + X[3] * P[3] + X[6] * P[6];
    const double Dp10 = X[1] * P[0] + X[4] * P[3] + X[7] * P[6];
    const double Dp11 = X[1] * P[1] + X[4] * P[4] + X[7] * P[7];
    const double Dp20 = X[2] * P[0] + X[5] * P[3] + X[8] * P[6];
    const double Dp21 = X[2] * P[1] + X[5] * P[4] + X[8] * P[7];
    const double Dp22 = X[2] * P[2] + X[5] * P[5] + X[8] * P[8];

    out[0 * NVOX + id] = (float)Dp00;
    out[1 * NVOX + id] = (float)Dp10;
    out[2 * NVOX + id] = (float)Dp11;
    out[3 * NVOX + id] = (float)Dp20;
    out[4 * NVOX + id] = (float)Dp21;
    out[5 * NVOX + id] = (float)Dp22;
}

extern "C" void kernel_launch(void* const* d_in, const int* in_sizes, int n_in,
                              void* d_out, int out_size, void* d_ws, size_t ws_size,
                              hipStream_t stream) {
    const float* dti = (const float*)d_in[0];
    const float* ddf = (const float*)d_in[1];
    float* out = (float*)d_out;
    const int nblk = NVOX / 256;
    hipLaunchKernelGGL(warp_dti_kernel, dim3(nblk), dim3(256), 0, stream,
                       dti, ddf, out);
}